// Round 2
// baseline (191.705 us; speedup 1.0000x reference)
//
#include <hip/hip_runtime.h>
#include <hip/hip_cooperative_groups.h>
#include <math.h>

namespace cg = cooperative_groups;

#define LN_EPS 1e-5f
#define NM 64
#define E_DIM 128
#define NH 4
#define TOTAL 537600               // 64 * 8400
#define SCALE 0.17677669529663687f // 1/sqrt(32)
#define LOG2E 1.4426950408889634f
#define NPTS 8192
#define XMIN -8.0f
#define XRANGE 16.0f
#define H_STEP (XRANGE / (NPTS - 1))
#define INV_H ((float)(NPTS - 1) / XRANGE)
#define GRID 256

// ws layout (floats) — shared by fused and fallback paths:
//   [0..255]     pool_part[m*4+s]   (64 modes x 4 splits, raw sums)
//   [256..8447]  Ftab[NPTS]         (univariate refined-function table, 16B aligned)

__device__ __forceinline__ float block_sum256(float v, float* scratch) {
#pragma unroll
    for (int off = 32; off; off >>= 1) v += __shfl_down(v, off);
    if ((threadIdx.x & 63) == 0) scratch[threadIdx.x >> 6] = v;
    __syncthreads();
    float r = (scratch[0] + scratch[1]) + (scratch[2] + scratch[3]);
    __syncthreads();
    return r;
}

// ============================ fused cooperative kernel ============================
__global__ __launch_bounds__(256) void fused_kernel(
    const float* __restrict__ coeff,
    const float* __restrict__ protos,
    const float* __restrict__ q_w, const float* __restrict__ q_b,
    const float* __restrict__ q_g, const float* __restrict__ q_beta,
    const float* __restrict__ k_w, const float* __restrict__ k_b,
    const float* __restrict__ k_g, const float* __restrict__ k_beta,
    const float* __restrict__ v_w, const float* __restrict__ v_b,
    const float* __restrict__ v_g, const float* __restrict__ v_beta,
    const float* __restrict__ out_w, const float* __restrict__ out_b,
    const float* __restrict__ gate_w, const float* __restrict__ gate_b,
    float* __restrict__ ws,
    float* __restrict__ outp) {
    __shared__ float Ft[NPTS];     // 32 KiB (phase 3)
    __shared__ float4 tabs[256];   // 4 KiB  (phase 2)
    __shared__ float scratch[4];

    cg::grid_group grid = cg::this_grid();
    int t = threadIdx.x;
    int bx = blockIdx.x;

    float* pool_part = ws;         // 256 floats
    float* Ftab      = ws + 256;   // NPTS floats (1 KiB offset -> 16B aligned)

    // ============ phase 1: pool partials (4 blocks per mode, as round-0) ============
    {
        int m = bx >> 2, s = bx & 3;
        const float4* p4 = reinterpret_cast<const float4*>(protos + (size_t)m * 25600);
        float acc = 0.f;
        for (int i = s * 1600 + t; i < (s + 1) * 1600; i += 256) {
            float4 v = p4[i];
            acc += (v.x + v.y) + (v.z + v.w);
        }
#pragma unroll
        for (int off = 32; off; off >>= 1) acc += __shfl_down(acc, off);
        if ((t & 63) == 0) scratch[t >> 6] = acc;
        __syncthreads();
        if (t == 0) pool_part[bx] = (scratch[0] + scratch[1]) + (scratch[2] + scratch[3]);
        __syncthreads();
    }

    // ---- q LayerNorm stats (pool-independent; overlaps other blocks' pooling) ----
    float lw = (t < E_DIM) ? q_w[t] : 0.f;
    float lb = (t < E_DIM) ? q_b[t] : 0.f;
    float mw = block_sum256(lw, scratch) * (1.0f / E_DIM);
    float mb = block_sum256(lb, scratch) * (1.0f / E_DIM);
    float dw = (t < E_DIM) ? (lw - mw) : 0.f;
    float db = (t < E_DIM) ? (lb - mb) : 0.f;
    float a2 = block_sum256(dw * dw, scratch) * (1.0f / E_DIM);
    float a1 = block_sum256(dw * db, scratch) * (1.0f / E_DIM);
    float a0 = block_sum256(db * db, scratch) * (1.0f / E_DIM);

    grid.sync();

    // ============ phase 2: build tabs (redundant per block), as round-0 ============
    {
        int m = t >> 2, h = t & 3;

        float p = pool_part[t];
        p += __shfl_xor(p, 1);
        p += __shfl_xor(p, 2);
        p *= (1.0f / 25600.0f);

        float kin[32], vin[32];
        float sk = 0.f, sv = 0.f;
#pragma unroll
        for (int j = 0; j < 32; ++j) {
            int e = h * 32 + j;
            kin[j] = fmaf(p, k_w[e], k_b[e]);
            vin[j] = fmaf(p, v_w[e], v_b[e]);
            sk += kin[j];
            sv += vin[j];
        }
        sk += __shfl_xor(sk, 1); sk += __shfl_xor(sk, 2);
        sv += __shfl_xor(sv, 1); sv += __shfl_xor(sv, 2);
        float muk = sk * (1.0f / E_DIM), muv = sv * (1.0f / E_DIM);
        float vk = 0.f, vv = 0.f;
#pragma unroll
        for (int j = 0; j < 32; ++j) {
            float dk = kin[j] - muk, dv = vin[j] - muv;
            vk = fmaf(dk, dk, vk);
            vv = fmaf(dv, dv, vv);
        }
        vk += __shfl_xor(vk, 1); vk += __shfl_xor(vk, 2);
        vv += __shfl_xor(vv, 1); vv += __shfl_xor(vv, 2);
        float rk = rsqrtf(vk * (1.0f / E_DIM) + LN_EPS);
        float rv = rsqrtf(vv * (1.0f / E_DIM) + LN_EPS);

        float kc = 0.f, k1 = 0.f, kb = 0.f, vwv = 0.f;
#pragma unroll
        for (int j = 0; j < 32; ++j) {
            int e = h * 32 + j;
            float key = fmaf((kin[j] - muk) * rk, k_g[e], k_beta[e]);
            float val = fmaf((vin[j] - muv) * rv, v_g[e], v_beta[e]);
            kc = fmaf((q_w[e] - mw) * q_g[e], key, kc);
            k1 = fmaf((q_b[e] - mb) * q_g[e], key, k1);
            kb = fmaf(q_beta[e], key, kb);
            vwv = fmaf(val, out_w[e], vwv);
        }
        const float SL = SCALE * LOG2E;
        tabs[h * 64 + m] = make_float4(SL * kc, SL * k1, SL * kb, vwv);
        __syncthreads();
    }

    // ---- evaluate F: 32 grid points per block, 8 lanes per point ----
    {
        int pt   = t >> 3;         // 0..31
        int sub  = t & 7;
        int head = sub >> 1;       // 0..3   (t bits 1,2)
        int half = sub & 1;        // 0..1   (t bit 0) -> 32 modes each
        int jpt = bx * 32 + pt;
        float x = fmaf((float)jpt, H_STEP, XMIN);
        float var = fmaf(x, fmaf(x, a2, 2.0f * a1), a0);
        float r = rsqrtf(var + LN_EPS);
        float al = r * x, be = r;
        const float4* th = tabs + head * 64 + half * 32;
        float den = 0.f, num = 0.f;
#pragma unroll
        for (int mm = 0; mm < 32; ++mm) {
            float4 tv = th[mm];
            float s = fmaf(al, tv.x, fmaf(be, tv.y, tv.z));
            float e = exp2f(s);
            den += e;
            num = fmaf(e, tv.w, num);
        }
        // combine mode-halves (t bit 0), then sum ratios over heads (t bits 1,2)
        den += __shfl_xor(den, 1);
        num += __shfl_xor(num, 1);
        float ratio = num / den;
        ratio += __shfl_xor(ratio, 2);
        ratio += __shfl_xor(ratio, 4);
        if (sub == 0) Ftab[jpt] = out_b[0] + ratio;
    }

    grid.sync();

    // ============ phase 3: apply (lerp + gate), grid-stride ============
    {
        const float4* F4 = (const float4*)Ftab;
        float4* Fs4 = (float4*)Ft;
#pragma unroll
        for (int k2 = 0; k2 < NPTS / 4 / 256; ++k2)
            Fs4[t + k2 * 256] = F4[t + k2 * 256];
        __syncthreads();

        const float4* coeff4 = (const float4*)coeff;
        float4* out4 = (float4*)outp;
        float gw0 = gate_w[0], gw1 = gate_w[1], gb = gate_b[0];
        for (int idx = bx * 256 + t; idx < TOTAL / 4; idx += GRID * 256) {
            float4 c4 = coeff4[idx];
            float c[4] = {c4.x, c4.y, c4.z, c4.w};
            float o[4];
#pragma unroll
            for (int i = 0; i < 4; ++i) {
                float u = (c[i] - XMIN) * INV_H;
                u = fminf(fmaxf(u, 0.0f), (float)(NPTS - 2));
                float jf = floorf(u);
                int j = (int)jf;
                float f = u - jf;
                float F0 = Ft[j], F1 = Ft[j + 1];
                float Fv = fmaf(f, F1 - F0, F0);
                float z = fmaf(c[i], gw0, fmaf(Fv, gw1, gb));
                float g = 1.0f / (1.0f + __expf(-z));
                o[i] = fmaf(g, Fv - c[i], c[i]);
            }
            out4[idx] = make_float4(o[0], o[1], o[2], o[3]);
        }
    }
}

// ============================ fallback path (round-0, verified) ============================
__global__ __launch_bounds__(256) void pool_kernel(const float* __restrict__ protos,
                                                   float* __restrict__ pool_part) {
    int bx = blockIdx.x;
    int m = bx >> 2, s = bx & 3;
    const float4* p4 = reinterpret_cast<const float4*>(protos + (size_t)m * 25600);
    float acc = 0.f;
    for (int i = s * 1600 + threadIdx.x; i < (s + 1) * 1600; i += 256) {
        float4 v = p4[i];
        acc += (v.x + v.y) + (v.z + v.w);
    }
#pragma unroll
    for (int off = 32; off; off >>= 1) acc += __shfl_down(acc, off);
    __shared__ float w[4];
    if ((threadIdx.x & 63) == 0) w[threadIdx.x >> 6] = acc;
    __syncthreads();
    if (threadIdx.x == 0) pool_part[bx] = (w[0] + w[1]) + (w[2] + w[3]);
}

__global__ __launch_bounds__(256) void build_kernel(
    const float* __restrict__ pool_part,
    const float* __restrict__ q_w, const float* __restrict__ q_b,
    const float* __restrict__ q_g, const float* __restrict__ q_beta,
    const float* __restrict__ k_w, const float* __restrict__ k_b,
    const float* __restrict__ k_g, const float* __restrict__ k_beta,
    const float* __restrict__ v_w, const float* __restrict__ v_b,
    const float* __restrict__ v_g, const float* __restrict__ v_beta,
    const float* __restrict__ out_w, const float* __restrict__ out_b,
    float* __restrict__ Ftab) {
    __shared__ float4 tabs[256];
    __shared__ float scratch[4];
    int t = threadIdx.x;
    int m = t >> 2, h = t & 3;

    float lw = (t < E_DIM) ? q_w[t] : 0.f;
    float lb = (t < E_DIM) ? q_b[t] : 0.f;
    float mw = block_sum256(lw, scratch) * (1.0f / E_DIM);
    float mb = block_sum256(lb, scratch) * (1.0f / E_DIM);
    float dw = (t < E_DIM) ? (lw - mw) : 0.f;
    float db = (t < E_DIM) ? (lb - mb) : 0.f;
    float a2 = block_sum256(dw * dw, scratch) * (1.0f / E_DIM);
    float a1 = block_sum256(dw * db, scratch) * (1.0f / E_DIM);
    float a0 = block_sum256(db * db, scratch) * (1.0f / E_DIM);

    float p = pool_part[t];
    p += __shfl_xor(p, 1);
    p += __shfl_xor(p, 2);
    p *= (1.0f / 25600.0f);

    float kin[32], vin[32];
    float sk = 0.f, sv = 0.f;
#pragma unroll
    for (int j = 0; j < 32; ++j) {
        int e = h * 32 + j;
        kin[j] = fmaf(p, k_w[e], k_b[e]);
        vin[j] = fmaf(p, v_w[e], v_b[e]);
        sk += kin[j];
        sv += vin[j];
    }
    sk += __shfl_xor(sk, 1); sk += __shfl_xor(sk, 2);
    sv += __shfl_xor(sv, 1); sv += __shfl_xor(sv, 2);
    float muk = sk * (1.0f / E_DIM), muv = sv * (1.0f / E_DIM);
    float vk = 0.f, vv = 0.f;
#pragma unroll
    for (int j = 0; j < 32; ++j) {
        float dk = kin[j] - muk, dv = vin[j] - muv;
        vk = fmaf(dk, dk, vk);
        vv = fmaf(dv, dv, vv);
    }
    vk += __shfl_xor(vk, 1); vk += __shfl_xor(vk, 2);
    vv += __shfl_xor(vv, 1); vv += __shfl_xor(vv, 2);
    float rk = rsqrtf(vk * (1.0f / E_DIM) + LN_EPS);
    float rv = rsqrtf(vv * (1.0f / E_DIM) + LN_EPS);

    float kc = 0.f, k1 = 0.f, kb = 0.f, vwv = 0.f;
#pragma unroll
    for (int j = 0; j < 32; ++j) {
        int e = h * 32 + j;
        float key = fmaf((kin[j] - muk) * rk, k_g[e], k_beta[e]);
        float val = fmaf((vin[j] - muv) * rv, v_g[e], v_beta[e]);
        kc = fmaf((q_w[e] - mw) * q_g[e], key, kc);
        k1 = fmaf((q_b[e] - mb) * q_g[e], key, k1);
        kb = fmaf(q_beta[e], key, kb);
        vwv = fmaf(val, out_w[e], vwv);
    }
    const float SL = SCALE * LOG2E;
    tabs[h * 64 + m] = make_float4(SL * kc, SL * k1, SL * kb, vwv);
    __syncthreads();

    int jpt = blockIdx.x * 256 + t;
    float x = fmaf((float)jpt, H_STEP, XMIN);
    float var = fmaf(x, fmaf(x, a2, 2.0f * a1), a0);
    float r = rsqrtf(var + LN_EPS);
    float al = r * x, be = r;
    float Fv = out_b[0];
#pragma unroll
    for (int hh = 0; hh < NH; ++hh) {
        const float4* th = tabs + hh * 64;
        float den = 0.f, num = 0.f;
#pragma unroll 8
        for (int mm = 0; mm < NM; ++mm) {
            float4 tv = th[mm];
            float s = fmaf(al, tv.x, fmaf(be, tv.y, tv.z));
            float e = exp2f(s);
            den += e;
            num = fmaf(e, tv.w, num);
        }
        Fv += num / den;
    }
    Ftab[jpt] = Fv;
}

__global__ __launch_bounds__(256) void apply_kernel(
    const float4* __restrict__ coeff4,
    const float* __restrict__ Ftab_g,
    const float* __restrict__ gate_w,
    const float* __restrict__ gate_b,
    float4* __restrict__ out4) {
    __shared__ float Ft[NPTS];
    {
        const float4* F4 = (const float4*)Ftab_g;
        float4* Fs4 = (float4*)Ft;
#pragma unroll
        for (int k = 0; k < NPTS / 4 / 256; ++k)
            Fs4[threadIdx.x + k * 256] = F4[threadIdx.x + k * 256];
    }
    __syncthreads();

    int idx = blockIdx.x * 256 + threadIdx.x;
    float4 c4 = coeff4[idx];
    float c[4] = {c4.x, c4.y, c4.z, c4.w};
    float gw0 = gate_w[0], gw1 = gate_w[1], gb = gate_b[0];
    float o[4];
#pragma unroll
    for (int i = 0; i < 4; ++i) {
        float u = (c[i] - XMIN) * INV_H;
        u = fminf(fmaxf(u, 0.0f), (float)(NPTS - 2));
        float jf = floorf(u);
        int j = (int)jf;
        float f = u - jf;
        float F0 = Ft[j], F1 = Ft[j + 1];
        float Fv = fmaf(f, F1 - F0, F0);
        float z = fmaf(c[i], gw0, fmaf(Fv, gw1, gb));
        float g = 1.0f / (1.0f + __expf(-z));
        o[i] = fmaf(g, Fv - c[i], c[i]);
    }
    out4[idx] = make_float4(o[0], o[1], o[2], o[3]);
}

extern "C" void kernel_launch(void* const* d_in, const int* in_sizes, int n_in,
                              void* d_out, int out_size, void* d_ws, size_t ws_size,
                              hipStream_t stream) {
    const float* coeff   = (const float*)d_in[0];
    const float* protos  = (const float*)d_in[1];
    const float* q_w     = (const float*)d_in[2];
    const float* q_b     = (const float*)d_in[3];
    const float* q_g     = (const float*)d_in[4];
    const float* q_beta  = (const float*)d_in[5];
    const float* k_w     = (const float*)d_in[6];
    const float* k_b     = (const float*)d_in[7];
    const float* k_g     = (const float*)d_in[8];
    const float* k_beta  = (const float*)d_in[9];
    const float* v_w     = (const float*)d_in[10];
    const float* v_b     = (const float*)d_in[11];
    const float* v_g     = (const float*)d_in[12];
    const float* v_beta  = (const float*)d_in[13];
    const float* out_w   = (const float*)d_in[14];
    const float* out_b   = (const float*)d_in[15];
    const float* gate_w  = (const float*)d_in[16];
    const float* gate_b  = (const float*)d_in[17];
    float* ws   = (float*)d_ws;
    float* outp = (float*)d_out;

    const float* c_coeff = coeff;
    void* args[] = {
        (void*)&c_coeff, (void*)&protos,
        (void*)&q_w, (void*)&q_b, (void*)&q_g, (void*)&q_beta,
        (void*)&k_w, (void*)&k_b, (void*)&k_g, (void*)&k_beta,
        (void*)&v_w, (void*)&v_b, (void*)&v_g, (void*)&v_beta,
        (void*)&out_w, (void*)&out_b, (void*)&gate_w, (void*)&gate_b,
        (void*)&ws, (void*)&outp,
    };
    hipError_t err = hipLaunchCooperativeKernel((const void*)fused_kernel,
                                                dim3(GRID), dim3(256), args, 0, stream);
    if (err != hipSuccess) {
        // fallback: verified 3-kernel path (same ws layout)
        float* pool_part = ws;
        float* Ftab      = ws + 256;
        pool_kernel<<<256, 256, 0, stream>>>(protos, pool_part);
        build_kernel<<<NPTS / 256, 256, 0, stream>>>(pool_part,
            q_w, q_b, q_g, q_beta, k_w, k_b, k_g, k_beta,
            v_w, v_b, v_g, v_beta, out_w, out_b, Ftab);
        apply_kernel<<<TOTAL / 4 / 256, 256, 0, stream>>>(
            (const float4*)coeff, Ftab, gate_w, gate_b, (float4*)d_out);
    }
}

// Round 3
// 117.657 us; speedup vs baseline: 1.6294x; 1.6294x over previous
//
#include <hip/hip_runtime.h>
#include <math.h>

#define LN_EPS 1e-5f
#define NM 64
#define E_DIM 128
#define NH 4
#define TOTAL 537600               // 64 * 8400
#define SCALE 0.17677669529663687f // 1/sqrt(32)
#define LOG2E 1.4426950408889634f
#define NPTS 8192
#define XMIN -8.0f
#define XRANGE 16.0f
#define H_STEP (XRANGE / (NPTS - 1))
#define INV_H ((float)(NPTS - 1) / XRANGE)

// ws layout (floats):
//   [0..255]     pool_part[m*4+s]   (64 modes x 4 splits, raw sums)
//   [256..8447]  Ftab[NPTS]         (univariate refined-function table)

// ---------------- pool: 256 blocks (4 per mode) x 256 threads ----------------
__global__ __launch_bounds__(256) void pool_kernel(const float* __restrict__ protos,
                                                   float* __restrict__ pool_part) {
    int bx = blockIdx.x;
    int m = bx >> 2, s = bx & 3;
    const float4* p4 = reinterpret_cast<const float4*>(protos + (size_t)m * 25600);
    float acc = 0.f;
    for (int i = s * 1600 + threadIdx.x; i < (s + 1) * 1600; i += 256) {
        float4 v = p4[i];
        acc += (v.x + v.y) + (v.z + v.w);
    }
#pragma unroll
    for (int off = 32; off; off >>= 1) acc += __shfl_down(acc, off);
    __shared__ float w[4];
    if ((threadIdx.x & 63) == 0) w[threadIdx.x >> 6] = acc;
    __syncthreads();
    if (threadIdx.x == 0) pool_part[bx] = (w[0] + w[1]) + (w[2] + w[3]);
}

// ---------------- build: 64 blocks x 256 threads, 128 points/block ----------------
// Each block: (redundant) q-stats + full tab4 in LDS, then evaluates 128 grid
// points of the univariate function F(x) = refined(coeff=x), 2 threads/point
// (each thread covers 2 heads x 64 modes; shfl_xor(1) combines).
__device__ __forceinline__ float block_sum256(float v, float* scratch) {
#pragma unroll
    for (int off = 32; off; off >>= 1) v += __shfl_down(v, off);
    if ((threadIdx.x & 63) == 0) scratch[threadIdx.x >> 6] = v;
    __syncthreads();
    float r = (scratch[0] + scratch[1]) + (scratch[2] + scratch[3]);
    __syncthreads();
    return r;
}

__global__ __launch_bounds__(256) void build_kernel(
    const float* __restrict__ pool_part,
    const float* __restrict__ q_w, const float* __restrict__ q_b,
    const float* __restrict__ q_g, const float* __restrict__ q_beta,
    const float* __restrict__ k_w, const float* __restrict__ k_b,
    const float* __restrict__ k_g, const float* __restrict__ k_beta,
    const float* __restrict__ v_w, const float* __restrict__ v_b,
    const float* __restrict__ v_g, const float* __restrict__ v_beta,
    const float* __restrict__ out_w, const float* __restrict__ out_b,
    float* __restrict__ Ftab) {
    __shared__ float4 tabs[256];
    __shared__ float scratch[4];
    int t = threadIdx.x;
    int m = t >> 2, h = t & 3;

    // ---- q LayerNorm stats (block-parallel over e; threads >=128 contribute 0) ----
    float lw = (t < E_DIM) ? q_w[t] : 0.f;
    float lb = (t < E_DIM) ? q_b[t] : 0.f;
    float mw = block_sum256(lw, scratch) * (1.0f / E_DIM);
    float mb = block_sum256(lb, scratch) * (1.0f / E_DIM);
    float dw = (t < E_DIM) ? (lw - mw) : 0.f;
    float db = (t < E_DIM) ? (lb - mb) : 0.f;
    float a2 = block_sum256(dw * dw, scratch) * (1.0f / E_DIM);
    float a1 = block_sum256(dw * db, scratch) * (1.0f / E_DIM);
    float a0 = block_sum256(db * db, scratch) * (1.0f / E_DIM);

    // ---- pooled[m]: 4 raw partials per mode in lanes m*4+{0..3} ----
    float p = pool_part[t];
    p += __shfl_xor(p, 1);
    p += __shfl_xor(p, 2);
    p *= (1.0f / 25600.0f);

    // ---- key/value LN stats for mode m (4 lanes/mode, 32 e's each) ----
    float kin[32], vin[32];
    float sk = 0.f, sv = 0.f;
#pragma unroll
    for (int j = 0; j < 32; ++j) {
        int e = h * 32 + j;
        kin[j] = fmaf(p, k_w[e], k_b[e]);
        vin[j] = fmaf(p, v_w[e], v_b[e]);
        sk += kin[j];
        sv += vin[j];
    }
    sk += __shfl_xor(sk, 1); sk += __shfl_xor(sk, 2);
    sv += __shfl_xor(sv, 1); sv += __shfl_xor(sv, 2);
    float muk = sk * (1.0f / E_DIM), muv = sv * (1.0f / E_DIM);
    float vk = 0.f, vv = 0.f;
#pragma unroll
    for (int j = 0; j < 32; ++j) {
        float dk = kin[j] - muk, dv = vin[j] - muv;
        vk = fmaf(dk, dk, vk);
        vv = fmaf(dv, dv, vv);
    }
    vk += __shfl_xor(vk, 1); vk += __shfl_xor(vk, 2);
    vv += __shfl_xor(vv, 1); vv += __shfl_xor(vv, 2);
    float rk = rsqrtf(vk * (1.0f / E_DIM) + LN_EPS);
    float rv = rsqrtf(vv * (1.0f / E_DIM) + LN_EPS);

    // ---- per (m,h) score/value table entries ----
    float kc = 0.f, k1 = 0.f, kb = 0.f, vwv = 0.f;
#pragma unroll
    for (int j = 0; j < 32; ++j) {
        int e = h * 32 + j;
        float key = fmaf((kin[j] - muk) * rk, k_g[e], k_beta[e]);
        float val = fmaf((vin[j] - muv) * rv, v_g[e], v_beta[e]);
        kc = fmaf((q_w[e] - mw) * q_g[e], key, kc);
        k1 = fmaf((q_b[e] - mb) * q_g[e], key, k1);
        kb = fmaf(q_beta[e], key, kb);
        vwv = fmaf(val, out_w[e], vwv);
    }
    const float SL = SCALE * LOG2E;
    tabs[h * 64 + m] = make_float4(SL * kc, SL * k1, SL * kb, vwv);
    __syncthreads();

    // ---- evaluate F: 128 points/block, 2 threads/point (2 heads each) ----
    int pt  = t >> 1;          // 0..127
    int sub = t & 1;           // 0..1 -> heads {0,1} or {2,3}
    int jpt = blockIdx.x * 128 + pt;
    float x = fmaf((float)jpt, H_STEP, XMIN);
    float var = fmaf(x, fmaf(x, a2, 2.0f * a1), a0);
    float r = rsqrtf(var + LN_EPS);
    float al = r * x, be = r;
    float ratio = 0.f;
#pragma unroll
    for (int hh = 0; hh < 2; ++hh) {
        const float4* th = tabs + (sub * 2 + hh) * 64;
        float den = 0.f, num = 0.f;
#pragma unroll 8
        for (int mm = 0; mm < NM; ++mm) {
            float4 tv = th[mm];
            float s = fmaf(al, tv.x, fmaf(be, tv.y, tv.z));
            float e = exp2f(s);
            den += e;
            num = fmaf(e, tv.w, num);
        }
        ratio += num / den;
    }
    ratio += __shfl_xor(ratio, 1);
    if (sub == 0) Ftab[jpt] = out_b[0] + ratio;
}

// ---------------- apply: elementwise lerp + gate, 4 elems/thread ----------------
__global__ __launch_bounds__(256) void apply_kernel(
    const float4* __restrict__ coeff4,
    const float* __restrict__ Ftab_g,
    const float* __restrict__ gate_w,
    const float* __restrict__ gate_b,
    float4* __restrict__ out4) {
    __shared__ float Ft[NPTS];
    {
        const float4* F4 = (const float4*)Ftab_g;
        float4* Fs4 = (float4*)Ft;
#pragma unroll
        for (int k = 0; k < NPTS / 4 / 256; ++k)
            Fs4[threadIdx.x + k * 256] = F4[threadIdx.x + k * 256];
    }
    __syncthreads();

    int idx = blockIdx.x * 256 + threadIdx.x;  // 525*256 float4 = 537600 elems
    float4 c4 = coeff4[idx];
    float c[4] = {c4.x, c4.y, c4.z, c4.w};
    float gw0 = gate_w[0], gw1 = gate_w[1], gb = gate_b[0];
    float o[4];
#pragma unroll
    for (int i = 0; i < 4; ++i) {
        float u = (c[i] - XMIN) * INV_H;
        u = fminf(fmaxf(u, 0.0f), (float)(NPTS - 2));  // j <= NPTS-2 (F flat at edges)
        float jf = floorf(u);
        int j = (int)jf;
        float f = u - jf;
        float F0 = Ft[j], F1 = Ft[j + 1];
        float Fv = fmaf(f, F1 - F0, F0);
        float z = fmaf(c[i], gw0, fmaf(Fv, gw1, gb));
        float g = 1.0f / (1.0f + __expf(-z));
        o[i] = fmaf(g, Fv - c[i], c[i]);  // g*refined + (1-g)*c
    }
    out4[idx] = make_float4(o[0], o[1], o[2], o[3]);
}

extern "C" void kernel_launch(void* const* d_in, const int* in_sizes, int n_in,
                              void* d_out, int out_size, void* d_ws, size_t ws_size,
                              hipStream_t stream) {
    const float* coeff   = (const float*)d_in[0];
    const float* protos  = (const float*)d_in[1];
    const float* q_w     = (const float*)d_in[2];
    const float* q_b     = (const float*)d_in[3];
    const float* q_g     = (const float*)d_in[4];
    const float* q_beta  = (const float*)d_in[5];
    const float* k_w     = (const float*)d_in[6];
    const float* k_b     = (const float*)d_in[7];
    const float* k_g     = (const float*)d_in[8];
    const float* k_beta  = (const float*)d_in[9];
    const float* v_w     = (const float*)d_in[10];
    const float* v_b     = (const float*)d_in[11];
    const float* v_g     = (const float*)d_in[12];
    const float* v_beta  = (const float*)d_in[13];
    const float* out_w   = (const float*)d_in[14];
    const float* out_b   = (const float*)d_in[15];
    const float* gate_w  = (const float*)d_in[16];
    const float* gate_b  = (const float*)d_in[17];

    float* ws        = (float*)d_ws;
    float* pool_part = ws;          // 256 floats
    float* Ftab      = ws + 256;    // NPTS floats (1 KiB offset -> 16B aligned)

    pool_kernel<<<256, 256, 0, stream>>>(protos, pool_part);
    build_kernel<<<NPTS / 128, 256, 0, stream>>>(pool_part,
        q_w, q_b, q_g, q_beta, k_w, k_b, k_g, k_beta,
        v_w, v_b, v_g, v_beta, out_w, out_b, Ftab);
    apply_kernel<<<TOTAL / 4 / 256, 256, 0, stream>>>(
        (const float4*)coeff, Ftab, gate_w, gate_b, (float4*)d_out);
}

// Round 4
// 116.891 us; speedup vs baseline: 1.6400x; 1.0065x over previous
//
#include <hip/hip_runtime.h>
#include <math.h>

#define LN_EPS 1e-5f
#define NM 64
#define E_DIM 128
#define NH 4
#define TOTAL 537600               // 64 * 8400
#define SCALE 0.17677669529663687f // 1/sqrt(32)
#define LOG2E 1.4426950408889634f
#define NPTS 8192
#define XMIN -8.0f
#define XRANGE 16.0f
#define H_STEP (XRANGE / (NPTS - 1))
#define INV_H ((float)(NPTS - 1) / XRANGE)

// ws layout (floats):
//   [0..255]     pool_part[m*4+s]   (64 modes x 4 splits, raw sums)
//   [256..8447]  Ftab[NPTS]         (univariate refined-function table)

// ---------------- pool: 256 blocks (4 per mode) x 256 threads ----------------
__global__ __launch_bounds__(256) void pool_kernel(const float* __restrict__ protos,
                                                   float* __restrict__ pool_part) {
    int bx = blockIdx.x;
    int m = bx >> 2, s = bx & 3;
    const float4* p4 = reinterpret_cast<const float4*>(protos + (size_t)m * 25600);
    float acc = 0.f;
    for (int i = s * 1600 + threadIdx.x; i < (s + 1) * 1600; i += 256) {
        float4 v = p4[i];
        acc += (v.x + v.y) + (v.z + v.w);
    }
#pragma unroll
    for (int off = 32; off; off >>= 1) acc += __shfl_down(acc, off);
    __shared__ float w[4];
    if ((threadIdx.x & 63) == 0) w[threadIdx.x >> 6] = acc;
    __syncthreads();
    if (threadIdx.x == 0) pool_part[bx] = (w[0] + w[1]) + (w[2] + w[3]);
}

// ---------------- build: 256 blocks x 256 threads, 32 points/block ----------------
// Each block: (redundant) q-stats + full tab4 in LDS, then evaluates 32 grid
// points of the univariate function F(x) = refined(coeff=x), 8 lanes/point
// (each lane covers 1 head x 32 modes; shfl_xor combines). Scheme verified in
// the round-2 cooperative kernel (passed absmax 3.9e-3).
__device__ __forceinline__ float block_sum256(float v, float* scratch) {
#pragma unroll
    for (int off = 32; off; off >>= 1) v += __shfl_down(v, off);
    if ((threadIdx.x & 63) == 0) scratch[threadIdx.x >> 6] = v;
    __syncthreads();
    float r = (scratch[0] + scratch[1]) + (scratch[2] + scratch[3]);
    __syncthreads();
    return r;
}

__global__ __launch_bounds__(256) void build_kernel(
    const float* __restrict__ pool_part,
    const float* __restrict__ q_w, const float* __restrict__ q_b,
    const float* __restrict__ q_g, const float* __restrict__ q_beta,
    const float* __restrict__ k_w, const float* __restrict__ k_b,
    const float* __restrict__ k_g, const float* __restrict__ k_beta,
    const float* __restrict__ v_w, const float* __restrict__ v_b,
    const float* __restrict__ v_g, const float* __restrict__ v_beta,
    const float* __restrict__ out_w, const float* __restrict__ out_b,
    float* __restrict__ Ftab) {
    __shared__ float4 tabs[256];
    __shared__ float scratch[4];
    int t = threadIdx.x;
    int m = t >> 2, h = t & 3;

    // ---- q LayerNorm stats (block-parallel over e; threads >=128 contribute 0) ----
    float lw = (t < E_DIM) ? q_w[t] : 0.f;
    float lb = (t < E_DIM) ? q_b[t] : 0.f;
    float mw = block_sum256(lw, scratch) * (1.0f / E_DIM);
    float mb = block_sum256(lb, scratch) * (1.0f / E_DIM);
    float dw = (t < E_DIM) ? (lw - mw) : 0.f;
    float db = (t < E_DIM) ? (lb - mb) : 0.f;
    float a2 = block_sum256(dw * dw, scratch) * (1.0f / E_DIM);
    float a1 = block_sum256(dw * db, scratch) * (1.0f / E_DIM);
    float a0 = block_sum256(db * db, scratch) * (1.0f / E_DIM);

    // ---- pooled[m]: 4 raw partials per mode in lanes m*4+{0..3} ----
    float p = pool_part[t];
    p += __shfl_xor(p, 1);
    p += __shfl_xor(p, 2);
    p *= (1.0f / 25600.0f);

    // ---- key/value LN stats for mode m (4 lanes/mode, 32 e's each) ----
    float kin[32], vin[32];
    float sk = 0.f, sv = 0.f;
#pragma unroll
    for (int j = 0; j < 32; ++j) {
        int e = h * 32 + j;
        kin[j] = fmaf(p, k_w[e], k_b[e]);
        vin[j] = fmaf(p, v_w[e], v_b[e]);
        sk += kin[j];
        sv += vin[j];
    }
    sk += __shfl_xor(sk, 1); sk += __shfl_xor(sk, 2);
    sv += __shfl_xor(sv, 1); sv += __shfl_xor(sv, 2);
    float muk = sk * (1.0f / E_DIM), muv = sv * (1.0f / E_DIM);
    float vk = 0.f, vv = 0.f;
#pragma unroll
    for (int j = 0; j < 32; ++j) {
        float dk = kin[j] - muk, dv = vin[j] - muv;
        vk = fmaf(dk, dk, vk);
        vv = fmaf(dv, dv, vv);
    }
    vk += __shfl_xor(vk, 1); vk += __shfl_xor(vk, 2);
    vv += __shfl_xor(vv, 1); vv += __shfl_xor(vv, 2);
    float rk = rsqrtf(vk * (1.0f / E_DIM) + LN_EPS);
    float rv = rsqrtf(vv * (1.0f / E_DIM) + LN_EPS);

    // ---- per (m,h) score/value table entries ----
    float kc = 0.f, k1 = 0.f, kb = 0.f, vwv = 0.f;
#pragma unroll
    for (int j = 0; j < 32; ++j) {
        int e = h * 32 + j;
        float key = fmaf((kin[j] - muk) * rk, k_g[e], k_beta[e]);
        float val = fmaf((vin[j] - muv) * rv, v_g[e], v_beta[e]);
        kc = fmaf((q_w[e] - mw) * q_g[e], key, kc);
        k1 = fmaf((q_b[e] - mb) * q_g[e], key, k1);
        kb = fmaf(q_beta[e], key, kb);
        vwv = fmaf(val, out_w[e], vwv);
    }
    const float SL = SCALE * LOG2E;
    tabs[h * 64 + m] = make_float4(SL * kc, SL * k1, SL * kb, vwv);
    __syncthreads();

    // ---- evaluate F: 32 points/block, 8 lanes/point ----
    int pt   = t >> 3;         // 0..31
    int sub  = t & 7;
    int head = sub >> 1;       // 0..3   (t bits 1,2)
    int half = sub & 1;        // 0..1   (t bit 0) -> 32 modes each
    int jpt = blockIdx.x * 32 + pt;
    float x = fmaf((float)jpt, H_STEP, XMIN);
    float var = fmaf(x, fmaf(x, a2, 2.0f * a1), a0);
    float r = rsqrtf(var + LN_EPS);
    float al = r * x, be = r;
    const float4* th = tabs + head * 64 + half * 32;
    float den = 0.f, num = 0.f;
#pragma unroll
    for (int mm = 0; mm < 32; ++mm) {
        float4 tv = th[mm];
        float s = fmaf(al, tv.x, fmaf(be, tv.y, tv.z));
        float e = exp2f(s);
        den += e;
        num = fmaf(e, tv.w, num);
    }
    // combine mode-halves (t bit 0), then sum ratios over heads (t bits 1,2)
    den += __shfl_xor(den, 1);
    num += __shfl_xor(num, 1);
    float ratio = num / den;
    ratio += __shfl_xor(ratio, 2);
    ratio += __shfl_xor(ratio, 4);
    if (sub == 0) Ftab[jpt] = out_b[0] + ratio;
}

// ---------------- apply: elementwise lerp + gate, 4 elems/thread ----------------
__global__ __launch_bounds__(256) void apply_kernel(
    const float4* __restrict__ coeff4,
    const float* __restrict__ Ftab_g,
    const float* __restrict__ gate_w,
    const float* __restrict__ gate_b,
    float4* __restrict__ out4) {
    __shared__ float Ft[NPTS];
    {
        const float4* F4 = (const float4*)Ftab_g;
        float4* Fs4 = (float4*)Ft;
#pragma unroll
        for (int k = 0; k < NPTS / 4 / 256; ++k)
            Fs4[threadIdx.x + k * 256] = F4[threadIdx.x + k * 256];
    }
    __syncthreads();

    int idx = blockIdx.x * 256 + threadIdx.x;  // 525*256 float4 = 537600 elems
    float4 c4 = coeff4[idx];
    float c[4] = {c4.x, c4.y, c4.z, c4.w};
    float gw0 = gate_w[0], gw1 = gate_w[1], gb = gate_b[0];
    float o[4];
#pragma unroll
    for (int i = 0; i < 4; ++i) {
        float u = (c[i] - XMIN) * INV_H;
        u = fminf(fmaxf(u, 0.0f), (float)(NPTS - 2));  // j <= NPTS-2 (F flat at edges)
        float jf = floorf(u);
        int j = (int)jf;
        float f = u - jf;
        float F0 = Ft[j], F1 = Ft[j + 1];
        float Fv = fmaf(f, F1 - F0, F0);
        float z = fmaf(c[i], gw0, fmaf(Fv, gw1, gb));
        float g = 1.0f / (1.0f + __expf(-z));
        o[i] = fmaf(g, Fv - c[i], c[i]);  // g*refined + (1-g)*c
    }
    out4[idx] = make_float4(o[0], o[1], o[2], o[3]);
}

extern "C" void kernel_launch(void* const* d_in, const int* in_sizes, int n_in,
                              void* d_out, int out_size, void* d_ws, size_t ws_size,
                              hipStream_t stream) {
    const float* coeff   = (const float*)d_in[0];
    const float* protos  = (const float*)d_in[1];
    const float* q_w     = (const float*)d_in[2];
    const float* q_b     = (const float*)d_in[3];
    const float* q_g     = (const float*)d_in[4];
    const float* q_beta  = (const float*)d_in[5];
    const float* k_w     = (const float*)d_in[6];
    const float* k_b     = (const float*)d_in[7];
    const float* k_g     = (const float*)d_in[8];
    const float* k_beta  = (const float*)d_in[9];
    const float* v_w     = (const float*)d_in[10];
    const float* v_b     = (const float*)d_in[11];
    const float* v_g     = (const float*)d_in[12];
    const float* v_beta  = (const float*)d_in[13];
    const float* out_w   = (const float*)d_in[14];
    const float* out_b   = (const float*)d_in[15];
    const float* gate_w  = (const float*)d_in[16];
    const float* gate_b  = (const float*)d_in[17];

    float* ws        = (float*)d_ws;
    float* pool_part = ws;          // 256 floats
    float* Ftab      = ws + 256;    // NPTS floats (1 KiB offset -> 16B aligned)

    pool_kernel<<<256, 256, 0, stream>>>(protos, pool_part);
    build_kernel<<<NPTS / 32, 256, 0, stream>>>(pool_part,
        q_w, q_b, q_g, q_beta, k_w, k_b, k_g, k_beta,
        v_w, v_b, v_g, v_beta, out_w, out_b, Ftab);
    apply_kernel<<<TOTAL / 4 / 256, 256, 0, stream>>>(
        (const float4*)coeff, Ftab, gate_w, gate_b, (float4*)d_out);
}